// Round 13
// baseline (667.071 us; speedup 1.0000x reference)
//
#include <hip/hip_runtime.h>

// WL-conv factorized:  out[b,c,n,k] = Y0 + e1[c,k]*Y1 + e2[c,k]*Y2 + e3[c,k]*Y3
// with Ym = M^m labels and e_m the elementary symmetric polynomials of
// kernels[c,0..2,k] (per-step operators I + k_t∘M commute).
//
// SINGLE kernel, manual grid barriers (R12 lesson: pass duration = block
// latency; only fusion can remove boundaries/cold-L2/mask reloads):
//   grid = 1024 blocks x __launch_bounds__(256,4) = 4 blocks/CU x 256 CU
//   -> all blocks co-resident by construction (manual barrier is safe).
//   phase 0: int4 ballot-pack lig -> bits + labels -> swizzled bf16 Y0
//   gbar; phase 1..3: Y_{m+1} = M Y_m on matrix pipe (R11-proven inner loop);
//   masks wcs[16] loaded ONCE, reused all passes (same addresses each pass);
//   phase 3 fuses the combine epilogue.
// Barrier: per-block slots + epoch in d_ws; all targets are DELTAS from the
// epoch captured at kernel start (stable: epoch can't advance before all
// blocks arrive at barrier 1) -> robust to 0xAA poison / stale replay state.
//
// d_out (8 MB): final output only.
// d_ws: bits 8MB | ysw0|ysw1|ysw2 (0.5MB each) | slots[1024]+epoch @10MB.

#define BB 4
#define NN 4096
#define KK 16
#define CC 8
#define TT 3
#define WPR (NN / 64)
#define YSWZ (KK * NN)   // u16 elements per batch in swizzled Y (65536)
#define NBLK 1024

typedef unsigned long long u64;
typedef unsigned int u32;
typedef unsigned short u16;
typedef __attribute__((ext_vector_type(8))) short s16x8;
typedef __attribute__((ext_vector_type(4))) float f32x4v;

__device__ __forceinline__ u32 bf16_rne(float f) {
    u32 u = __float_as_uint(f);
    return (u + 0x7FFFu + ((u >> 16) & 1u)) >> 16;
}
__device__ __forceinline__ float bf16_f32(u32 h) {
    return __uint_as_float(h << 16);
}
__device__ __forceinline__ long ypos(int f, int s) {
    return ((long)(s >> 8) << 12) + (s & 3) * 1024 + ((s >> 7) & 1) * 512 +
           f * 32 + ((s >> 5) & 3) * 8 + ((s >> 2) & 7);
}

// byte (8 mask bits) -> 8 bf16 {0,1} packed in s16x8 (elem i = bit i)
__device__ __forceinline__ s16x8 expand8(u32 byt) {
    u32 n0 = byt & 0xFu, n1 = (byt >> 4) & 0xFu;
    u32 t0 = (n0 * 0x204081u) & 0x01010101u;
    u32 t1 = (n1 * 0x204081u) & 0x01010101u;
    u32 m0 = (t0 << 7) - t0;
    u32 m1 = (t1 << 7) - t1;
    union { u32 w[4]; s16x8 v; } u;
    u.w[0] = __builtin_amdgcn_perm(0u, m0, 0x0C010C00u) << 7;
    u.w[1] = __builtin_amdgcn_perm(0u, m0, 0x0C030C02u) << 7;
    u.w[2] = __builtin_amdgcn_perm(0u, m1, 0x0C010C00u) << 7;
    u.w[3] = __builtin_amdgcn_perm(0u, m1, 0x0C030C02u) << 7;
    return u.v;
}

// --------------------------------------------------------- grid barrier -----
__device__ __forceinline__ void gbar(u32* slots, u32* epoch, u32 target,
                                     int bid, int tid) {
    __threadfence();                     // release this block's data writes
    __syncthreads();
    if (tid == 0)
        __hip_atomic_store(slots + bid, target, __ATOMIC_RELEASE,
                           __HIP_MEMORY_SCOPE_AGENT);
    if (bid == 0) {
        for (;;) {
            bool ok = true;
#pragma unroll
            for (int j = 0; j < NBLK / 256; ++j)
                ok &= (__hip_atomic_load(slots + tid + j * 256, __ATOMIC_RELAXED,
                                         __HIP_MEMORY_SCOPE_AGENT) == target);
            if (__syncthreads_and(ok)) break;
            __builtin_amdgcn_s_sleep(8);
        }
        if (tid == 0)
            __hip_atomic_store(epoch, target, __ATOMIC_RELEASE,
                               __HIP_MEMORY_SCOPE_AGENT);
    } else if (tid == 0) {
        while (__hip_atomic_load(epoch, __ATOMIC_RELAXED,
                                 __HIP_MEMORY_SCOPE_AGENT) != target)
            __builtin_amdgcn_s_sleep(8);
    }
    __syncthreads();
    __threadfence();                     // acquire side
}

// ----------------------------------------------------- one spmm pass --------
// PASS 1/2: write swizzled bf16 yout. PASS 3: fused combine epilogue.
template<int PASS>
__device__ __forceinline__ void spmm_pass(
    const u64 (&wcs)[16], const u16* __restrict__ yin, u16* __restrict__ yout,
    const u16* __restrict__ ysw1, const u16* __restrict__ ysw2,
    const float* __restrict__ labels, const float* __restrict__ ker,
    float* __restrict__ out, int b, int row0, int tid, float (*red)[4][64])
{
    const int lane = tid & 63, ss = tid >> 6;
    const int n16 = lane & 15, g = lane >> 4;

    const u16* yb = yin + (long)b * YSWZ + (ss * 16) * 1024 + n16 * 32 + g * 8;
    s16x8 p0[4], p1[4];
#pragma unroll
    for (int i = 0; i < 4; ++i) {
        p0[i] = *(const s16x8*)(yb + i * 1024);
        p1[i] = *(const s16x8*)(yb + i * 1024 + 512);
    }

    f32x4v accA = {0.f, 0.f, 0.f, 0.f}, accB = {0.f, 0.f, 0.f, 0.f};
#pragma unroll
    for (int wi = 0; wi < 16; ++wi) {
        const int slot = wi & 3;
        s16x8 b0 = p0[slot], b1 = p1[slot];
        if (wi + 4 < 16) {
            p0[slot] = *(const s16x8*)(yb + (wi + 4) * 1024);
            p1[slot] = *(const s16x8*)(yb + (wi + 4) * 1024 + 512);
        }
        u64 h = wcs[wi] >> (g * 8);
        u32 lo8 = (u32)h & 0xFFu;
        u32 hi8 = ((u32)(h >> 32)) & 0xFFu;
        accA = __builtin_amdgcn_mfma_f32_16x16x32_bf16(expand8(lo8), b0, accA, 0, 0, 0);
        accB = __builtin_amdgcn_mfma_f32_16x16x32_bf16(expand8(hi8), b1, accB, 0, 0, 0);
    }

    f32x4v acc;
#pragma unroll
    for (int r = 0; r < 4; ++r) acc[r] = accA[r] + accB[r];

    if (ss != 0) {
#pragma unroll
        for (int r = 0; r < 4; ++r) red[ss - 1][r][lane] = acc[r];
    }
    __syncthreads();
    if (ss == 0) {
#pragma unroll
        for (int r = 0; r < 4; ++r)
            acc[r] += red[0][r][lane] + red[1][r][lane] + red[2][r][lane];

        const int s0 = row0 + 4 * g;                 // mult of 4: +r*1024
        const long base = (long)b * YSWZ + ypos(n16, s0);
        if (PASS < 3) {
#pragma unroll
            for (int r = 0; r < 4; ++r)
                yout[base + r * 1024] = (u16)bf16_rne(acc[r]);
        } else {
            float e1v[CC], e2v[CC], e3v[CC];
#pragma unroll
            for (int c = 0; c < CC; ++c) {
                float a = ker[(c * TT + 0) * KK + n16];
                float d = ker[(c * TT + 1) * KK + n16];
                float e = ker[(c * TT + 2) * KK + n16];
                e1v[c] = a + d + e;
                e2v[c] = a * d + a * e + d * e;
                e3v[c] = a * d * e;
            }
            float y1v[4], y2v[4];
#pragma unroll
            for (int r = 0; r < 4; ++r) {
                y1v[r] = bf16_f32(ysw1[base + r * 1024]);
                y2v[r] = bf16_f32(ysw2[base + r * 1024]);
            }
#pragma unroll
            for (int r = 0; r < 4; ++r) {
                int row = s0 + r;
                float y0 = labels[((long)b * NN + row) * KK + n16];
#pragma unroll
                for (int c = 0; c < CC; ++c)
                    out[(((long)b * CC + c) * NN + row) * KK + n16] =
                        y0 + e1v[c] * y1v[r] + e2v[c] * y2v[r] + e3v[c] * acc[r];
            }
        }
    }
}

// ----------------------------------------------------------- fused kernel ---
__global__ __launch_bounds__(256, 4)
void wl_all(const int* __restrict__ lig, const float* __restrict__ labels,
            const float* __restrict__ ker, float* __restrict__ out,
            u64* __restrict__ bits, u16* __restrict__ ysw0,
            u16* __restrict__ ysw1, u16* __restrict__ ysw2,
            u32* __restrict__ slots, u32* __restrict__ epoch)
{
    __shared__ float red[3][4][64];
    __shared__ u32 e0sh;
    const int bid = blockIdx.x;
    const int tid = threadIdx.x;

    if (tid == 0)
        e0sh = __hip_atomic_load(epoch, __ATOMIC_RELAXED,
                                 __HIP_MEMORY_SCOPE_AGENT);
    __syncthreads();
    const u32 E0 = e0sh;    // stable: epoch can't advance before barrier 1

    // ---------------- phase 0: pack + prep ---------------------------------
    {
        const int gid = bid * 256 + tid;
        if (gid < BB * KK * (NN / 4)) {              // 65536 prep tasks
            int s4 = (gid & (NN / 4 - 1)) * 4;
            int f  = (gid >> 10) & (KK - 1);
            int b  = gid >> 14;
            long base = (long)b * YSWZ + ypos(f, s4);
            const float* lp = labels + ((long)b * NN + s4) * KK + f;
#pragma unroll
            for (int j = 0; j < 4; ++j)
                ysw0[base + j * 1024] = (u16)bf16_rne(lp[j * KK]);
        }
        const int total = BB * (WPR / 4) * NN;       // 262,144 int4-groups
        const int nw    = (NBLK * 256) >> 6;         // 4096 wave-slots
        int wid  = gid >> 6;
        int lane = tid & 63;
        for (int o = wid; o < total; o += 2 * nw) {  // 2 loads in flight
            int o2 = o + nw;
            int n  = o & (NN - 1),  n2 = o2 & (NN - 1);
            int w4 = (o >> 12) & (WPR / 4 - 1), w42 = (o2 >> 12) & (WPR / 4 - 1);
            int b  = o >> 16,       b2 = o2 >> 16;
            int4 v  = *(const int4*)(lig + ((long)b  * NN + n ) * NN + w4  * 256 + lane * 4);
            int4 v2 = *(const int4*)(lig + ((long)b2 * NN + n2) * NN + w42 * 256 + lane * 4);
            u64 m0 = __ballot(v.x >= 1), m1 = __ballot(v.y >= 1);
            u64 m2 = __ballot(v.z >= 1), m3 = __ballot(v.w >= 1);
            if (lane == 0) {
                u64* bw = bits + ((long)b * WPR + 4 * w4) * NN + n;
                bw[0] = m0; bw[NN] = m1; bw[2 * NN] = m2; bw[3 * NN] = m3;
            }
            m0 = __ballot(v2.x >= 1); m1 = __ballot(v2.y >= 1);
            m2 = __ballot(v2.z >= 1); m3 = __ballot(v2.w >= 1);
            if (lane == 0) {
                u64* bw = bits + ((long)b2 * WPR + 4 * w42) * NN + n2;
                bw[0] = m0; bw[NN] = m1; bw[2 * NN] = m2; bw[3 * NN] = m3;
            }
        }
    }
    gbar(slots, epoch, E0 + 1, bid, tid);

    // ---------------- phases 1..3 ------------------------------------------
    const int b    = bid >> 8;
    const int rt   = bid & 255;
    const int row0 = rt * 16;
    const int lane = tid & 63, ss = tid >> 6;
    const int n16  = lane & 15;

    // masks: identical addresses every pass -> load ONCE, keep in registers
    u64 wcs[16];
    {
        const u64* bb = bits + ((long)b * WPR + ss * 16) * NN + row0 + n16;
#pragma unroll
        for (int wi = 0; wi < 16; ++wi) wcs[wi] = bb[(long)wi * NN];
    }

    spmm_pass<1>(wcs, ysw0, ysw1, nullptr, nullptr, nullptr, nullptr, nullptr,
                 b, row0, tid, red);
    gbar(slots, epoch, E0 + 2, bid, tid);
    spmm_pass<2>(wcs, ysw1, ysw2, nullptr, nullptr, nullptr, nullptr, nullptr,
                 b, row0, tid, red);
    gbar(slots, epoch, E0 + 3, bid, tid);
    spmm_pass<3>(wcs, ysw2, nullptr, ysw1, ysw2, labels, ker, out,
                 b, row0, tid, red);
}

// --------------------------------------------------------------- launch -----
extern "C" void kernel_launch(void* const* d_in, const int* in_sizes, int n_in,
                              void* d_out, int out_size, void* d_ws, size_t ws_size,
                              hipStream_t stream) {
    const float* labels = (const float*)d_in[0];   // [B,N,K] f32
    const int*   lig    = (const int*)d_in[1];     // [B,N,N] i32
    const float* ker    = (const float*)d_in[2];   // [C,T,K] f32
    float* out = (float*)d_out;

    u64* bits = (u64*)d_ws;                        // 8 MB
    u16* ysw0 = (u16*)((char*)d_ws + (long)BB * WPR * NN * 8);
    u16* ysw1 = ysw0 + (long)BB * YSWZ;
    u16* ysw2 = ysw1 + (long)BB * YSWZ;
    u32* slots = (u32*)((char*)d_ws + (10l << 20));   // 1024 u32 @ 10 MB
    u32* epoch = slots + NBLK;

    hipLaunchKernelGGL(wl_all, dim3(NBLK), dim3(256), 0, stream,
                       lig, labels, ker, out, bits, ysw0, ysw1, ysw2,
                       slots, epoch);
}

// Round 14
// 95.225 us; speedup vs baseline: 7.0052x; 7.0052x over previous
//
#include <hip/hip_runtime.h>

// WL-conv factorized:  out[b,c,n,k] = Y0 + e1[c,k]*Y1 + e2[c,k]*Y2 + e3[c,k]*Y3
// with Ym = M^m labels and e_m the elementary symmetric polynomials of
// kernels[c,0..2,k] (per-step operators I + k_t∘M commute).
//
// 4 stream-ordered kernels (R13 lesson: fusion-via-gridbarrier spills and
// dies; R12 lesson: stage-skewed pipelines pay block latency per stage):
//   prep: labels -> swizzled bf16 Y0 (65536 threads, trivial)
//   K1  : PACK FUSED: block (b,rt) int4-reads ITS OWN 16 lig rows (256 KB
//         contiguous, 2-deep pipeline), ballots into LDS bl[64][16], uses
//         masks from LDS for Y1 = M Y0, writes bits to global for K2/K3.
//         256 MB HBM read overlaps the MFMA work.
//   K2  : Y2 = M Y1 (masks from global bits; R11-proven inner loop)
//   K3  : Y3 = M Y2 + fused combine, VECTORIZED epilogue: wave0 parks the
//         16x16 Y1/Y2/Y3 tiles in LDS; all 4 waves write coalesced float4
//         (one channel's contiguous 1KB chunk per wave).
// Y chained in ypos-permuted MFMA-B-fragment layout (coalesced 1KB B loads):
//   ypos(f,s) = (s>>8)*4096 + (s&3)*1024 + ((s>>7)&1)*512
//             + f*32 + ((s>>5)&3)*8 + ((s>>2)&7)          [u16 units]
//
// d_out (8 MB): final output only.
// d_ws: bits 8MB | ysw0 | ysw1 | ysw2 (0.5 MB each, swizzled bf16).

#define BB 4
#define NN 4096
#define KK 16
#define CC 8
#define TT 3
#define WPR (NN / 64)
#define YSWZ (KK * NN)   // u16 elements per batch in swizzled Y (65536)

typedef unsigned long long u64;
typedef unsigned int u32;
typedef unsigned short u16;
typedef __attribute__((ext_vector_type(8))) short s16x8;
typedef __attribute__((ext_vector_type(4))) float f32x4v;

__device__ __forceinline__ u32 bf16_rne(float f) {
    u32 u = __float_as_uint(f);
    return (u + 0x7FFFu + ((u >> 16) & 1u)) >> 16;
}
__device__ __forceinline__ float bf16_f32(u32 h) {
    return __uint_as_float(h << 16);
}
__device__ __forceinline__ long ypos(int f, int s) {
    return ((long)(s >> 8) << 12) + (s & 3) * 1024 + ((s >> 7) & 1) * 512 +
           f * 32 + ((s >> 5) & 3) * 8 + ((s >> 2) & 7);
}

// byte (8 mask bits) -> 8 bf16 {0,1} packed in s16x8 (elem i = bit i)
__device__ __forceinline__ s16x8 expand8(u32 byt) {
    u32 n0 = byt & 0xFu, n1 = (byt >> 4) & 0xFu;
    u32 t0 = (n0 * 0x204081u) & 0x01010101u;
    u32 t1 = (n1 * 0x204081u) & 0x01010101u;
    u32 m0 = (t0 << 7) - t0;
    u32 m1 = (t1 << 7) - t1;
    union { u32 w[4]; s16x8 v; } u;
    u.w[0] = __builtin_amdgcn_perm(0u, m0, 0x0C010C00u) << 7;
    u.w[1] = __builtin_amdgcn_perm(0u, m0, 0x0C030C02u) << 7;
    u.w[2] = __builtin_amdgcn_perm(0u, m1, 0x0C010C00u) << 7;
    u.w[3] = __builtin_amdgcn_perm(0u, m1, 0x0C030C02u) << 7;
    return u.v;
}

// ---------------------------------------------------------------- prep ------
__global__ __launch_bounds__(256)
void prep_kernel(const float* __restrict__ labels, u16* __restrict__ ysw0) {
    int gid = blockIdx.x * 256 + threadIdx.x;            // 65536 tasks
    int s4 = (gid & (NN / 4 - 1)) * 4;
    int f  = (gid >> 10) & (KK - 1);
    int b  = gid >> 14;
    long base = (long)b * YSWZ + ypos(f, s4);            // s4 mult of 4: +j*1024
    const float* lp = labels + ((long)b * NN + s4) * KK + f;
#pragma unroll
    for (int j = 0; j < 4; ++j)
        ysw0[base + j * 1024] = (u16)bf16_rne(lp[j * KK]);
}

// ----------------------------------------------------------- spmm (MFMA) ----
// grid = BB*(NN/16) = 1024 blocks of 256 threads (4 waves, 4 blocks/CU).
// PASS 1: fused own-row pack (LDS masks) + spmm, writes bits + ysw1.
// PASS 2: spmm from global bits, writes ysw2.
// PASS 3: spmm + fused combine, vectorized epilogue.
template<int PASS>
__global__ __launch_bounds__(256, 4)
void spmm_k(const int* __restrict__ lig, u64* __restrict__ bits,
            const u16* __restrict__ yin, u16* __restrict__ yout,
            const u16* __restrict__ ysw1, const u16* __restrict__ ysw2,
            const float* __restrict__ labels, const float* __restrict__ ker,
            float* __restrict__ out)
{
    __shared__ float red[3][4][64];
    __shared__ u64 bl[64][16];                   // PASS1 masks [word][row] 8KB
    __shared__ float t1[16][16], t2[16][16], t3[16][16];  // PASS3 tiles 3KB
    const int bid = blockIdx.x;
    const int rt  = bid & (NN / 16 - 1);
    const int b   = bid >> 8;
    const int tid = threadIdx.x;
    const int lane = tid & 63, ss = tid >> 6;
    const int n16 = lane & 15, g = lane >> 4;
    const int row0 = rt * 16;

    if (PASS == 1) {
        // pack own 16 rows: wave ss handles tasks i=0..63 -> row=i&15,
        // w4 = ss*4 + (i>>4); int4 load -> 4 ballots; depth-2 pipeline.
        const int* lrow = lig + ((long)b * NN + row0) * NN;
        auto laddr = [&](int i) {
            int row = i & 15, w4 = ss * 4 + (i >> 4);
            return (const int4*)(lrow + (long)row * NN + w4 * 256 + lane * 4);
        };
        int4 v = *laddr(0);
        for (int i = 0; i < 64; ++i) {
            int4 vn;
            if (i + 1 < 64) vn = *laddr(i + 1);
            u64 m0 = __ballot(v.x >= 1);
            u64 m1 = __ballot(v.y >= 1);
            u64 m2 = __ballot(v.z >= 1);
            u64 m3 = __ballot(v.w >= 1);
            if (lane == 0) {
                int row = i & 15, wq = (ss * 4 + (i >> 4)) * 4;
                bl[wq + 0][row] = m0; bl[wq + 1][row] = m1;
                bl[wq + 2][row] = m2; bl[wq + 3][row] = m3;
                u64* bw = bits + ((long)b * WPR + wq) * NN + row0 + row;
                bw[0] = m0; bw[NN] = m1; bw[2 * NN] = m2; bw[3 * NN] = m3;
            }
            v = vn;
        }
        __syncthreads();
    }

    // masks for this wave's 16 words
    u64 wcs[16];
    if (PASS == 1) {
#pragma unroll
        for (int wi = 0; wi < 16; ++wi) wcs[wi] = bl[ss * 16 + wi][n16];
    } else {
        const u64* bb = bits + ((long)b * WPR + ss * 16) * NN + row0 + n16;
#pragma unroll
        for (int wi = 0; wi < 16; ++wi) wcs[wi] = bb[(long)wi * NN];
    }

    // B fragments: depth-4 register pipeline over coalesced 1KB segments
    const u16* yb = yin + (long)b * YSWZ + (ss * 16) * 1024 + n16 * 32 + g * 8;
    s16x8 p0[4], p1[4];
#pragma unroll
    for (int i = 0; i < 4; ++i) {
        p0[i] = *(const s16x8*)(yb + i * 1024);
        p1[i] = *(const s16x8*)(yb + i * 1024 + 512);
    }

    f32x4v accA = {0.f, 0.f, 0.f, 0.f}, accB = {0.f, 0.f, 0.f, 0.f};
#pragma unroll
    for (int wi = 0; wi < 16; ++wi) {
        const int slot = wi & 3;
        s16x8 b0 = p0[slot], b1 = p1[slot];
        if (wi + 4 < 16) {
            p0[slot] = *(const s16x8*)(yb + (wi + 4) * 1024);
            p1[slot] = *(const s16x8*)(yb + (wi + 4) * 1024 + 512);
        }
        u64 h = wcs[wi] >> (g * 8);
        u32 lo8 = (u32)h & 0xFFu;
        u32 hi8 = ((u32)(h >> 32)) & 0xFFu;
        accA = __builtin_amdgcn_mfma_f32_16x16x32_bf16(expand8(lo8), b0, accA, 0, 0, 0);
        accB = __builtin_amdgcn_mfma_f32_16x16x32_bf16(expand8(hi8), b1, accB, 0, 0, 0);
    }

    f32x4v acc;
#pragma unroll
    for (int r = 0; r < 4; ++r) acc[r] = accA[r] + accB[r];

    // PASS3: issue Y1/Y2 readbacks early (hide L2/L3 latency under reduce)
    const int s0 = row0 + 4 * g;
    const long ybase = (long)b * YSWZ + ypos(n16, s0);
    float y1v[4], y2v[4];
    if (PASS == 3 && ss == 0) {
#pragma unroll
        for (int r = 0; r < 4; ++r) {
            y1v[r] = bf16_f32(ysw1[ybase + r * 1024]);
            y2v[r] = bf16_f32(ysw2[ybase + r * 1024]);
        }
    }

    if (ss != 0) {
#pragma unroll
        for (int r = 0; r < 4; ++r) red[ss - 1][r][lane] = acc[r];
    }
    __syncthreads();
    if (ss == 0) {
#pragma unroll
        for (int r = 0; r < 4; ++r)
            acc[r] += red[0][r][lane] + red[1][r][lane] + red[2][r][lane];

        if (PASS < 3) {
#pragma unroll
            for (int r = 0; r < 4; ++r)
                yout[ybase + r * 1024] = (u16)bf16_rne(acc[r]);
        } else {
            // park tiles: row-in-tile = 4g+r, col = n16 (m89-verified D layout)
#pragma unroll
            for (int r = 0; r < 4; ++r) {
                t1[4 * g + r][n16] = y1v[r];
                t2[4 * g + r][n16] = y2v[r];
                t3[4 * g + r][n16] = acc[r];
            }
        }
    }

    if (PASS == 3) {
        __syncthreads();
        // all 256 threads: 2 coalesced float4 chunks each.
        // fi = tid + j*256: c = fi>>6, row = (fi>>2)&15, k4 = fi&3.
#pragma unroll
        for (int j = 0; j < 2; ++j) {
            int fi = tid + j * 256;
            int c = fi >> 6, row = (fi >> 2) & 15, k4 = fi & 3;
            const float4* kf = (const float4*)ker;
            float4 a = kf[(c * TT + 0) * 4 + k4];
            float4 d = kf[(c * TT + 1) * 4 + k4];
            float4 e = kf[(c * TT + 2) * 4 + k4];
            float4 e1, e2, e3;
            e1.x = a.x + d.x + e.x;               e1.y = a.y + d.y + e.y;
            e1.z = a.z + d.z + e.z;               e1.w = a.w + d.w + e.w;
            e2.x = a.x*d.x + a.x*e.x + d.x*e.x;   e2.y = a.y*d.y + a.y*e.y + d.y*e.y;
            e2.z = a.z*d.z + a.z*e.z + d.z*e.z;   e2.w = a.w*d.w + a.w*e.w + d.w*e.w;
            e3.x = a.x * d.x * e.x;               e3.y = a.y * d.y * e.y;
            e3.z = a.z * d.z * e.z;               e3.w = a.w * d.w * e.w;
            float4 y0 = *(const float4*)(labels + ((long)b * NN + row0 + row) * KK + k4 * 4);
            float4 v1 = *(const float4*)&t1[row][k4 * 4];
            float4 v2 = *(const float4*)&t2[row][k4 * 4];
            float4 v3 = *(const float4*)&t3[row][k4 * 4];
            float4 r;
            r.x = y0.x + e1.x * v1.x + e2.x * v2.x + e3.x * v3.x;
            r.y = y0.y + e1.y * v1.y + e2.y * v2.y + e3.y * v3.y;
            r.z = y0.z + e1.z * v1.z + e2.z * v2.z + e3.z * v3.z;
            r.w = y0.w + e1.w * v1.w + e2.w * v2.w + e3.w * v3.w;
            *(float4*)(out + (((long)b * CC + c) * NN + row0 + row) * KK + k4 * 4) = r;
        }
    }
}

// --------------------------------------------------------------- launch -----
extern "C" void kernel_launch(void* const* d_in, const int* in_sizes, int n_in,
                              void* d_out, int out_size, void* d_ws, size_t ws_size,
                              hipStream_t stream) {
    const float* labels = (const float*)d_in[0];   // [B,N,K] f32
    const int*   lig    = (const int*)d_in[1];     // [B,N,N] i32
    const float* ker    = (const float*)d_in[2];   // [C,T,K] f32
    float* out = (float*)d_out;

    u64* bits = (u64*)d_ws;                        // 8 MB
    u16* ysw0 = (u16*)((char*)d_ws + (long)BB * WPR * NN * 8);
    u16* ysw1 = ysw0 + (long)BB * YSWZ;
    u16* ysw2 = ysw1 + (long)BB * YSWZ;

    hipLaunchKernelGGL(prep_kernel, dim3(256), dim3(256), 0, stream,
                       labels, ysw0);

    dim3 sgrid(BB * (NN / 16));                    // 1024 blocks
    hipLaunchKernelGGL((spmm_k<1>), sgrid, dim3(256), 0, stream,
                       lig, bits, ysw0, ysw1, (const u16*)nullptr,
                       (const u16*)nullptr, (const float*)nullptr,
                       (const float*)nullptr, (float*)nullptr);
    hipLaunchKernelGGL((spmm_k<2>), sgrid, dim3(256), 0, stream,
                       (const int*)nullptr, bits, ysw1, ysw2,
                       (const u16*)nullptr, (const u16*)nullptr,
                       (const float*)nullptr, (const float*)nullptr,
                       (float*)nullptr);
    hipLaunchKernelGGL((spmm_k<3>), sgrid, dim3(256), 0, stream,
                       (const int*)nullptr, bits, ysw2, (u16*)nullptr,
                       ysw1, ysw2, labels, ker, out);
}

// Round 15
// 82.403 us; speedup vs baseline: 8.0952x; 1.1556x over previous
//
#include <hip/hip_runtime.h>

// WL-conv factorized:  out[b,c,n,k] = Y0 + e1[c,k]*Y1 + e2[c,k]*Y2 + e3[c,k]*Y3
// with Ym = M^m labels and e_m the elementary symmetric polynomials of
// kernels[c,0..2,k] (per-step operators I + k_t∘M commute).
//
// 4 stream-ordered kernels:
//   prep: labels -> swizzled bf16 Y0
//   K1  : block (b,rt) int4-reads ITS OWN 16 lig rows, ballots into LDS
//         bl[64][16], spmm from LDS masks, then writes the 8 KB mask tile to
//         global as ONE coalesced burst (R14 wrote 1M scattered 8B stores --
//         ~64MB of partial-line write transactions for 8MB payload).
//   K2  : Y2 = M Y1 (masks from block-contiguous bits)
//   K3  : Y3 = M Y2 + fused combine, vectorized float4 epilogue.
// bits layout: bits[((b*256+rt)*64 + w)*16 + r] -- producer coalesced,
// consumer = one 128B line per mask-load instr.
// Y chained in ypos-permuted MFMA-B-fragment layout (coalesced 1KB B loads).
//
// d_out (8 MB): final output only.
// d_ws: bits 8MB | ysw0 | ysw1 | ysw2 (0.5 MB each, swizzled bf16).

#define BB 4
#define NN 4096
#define KK 16
#define CC 8
#define TT 3
#define WPR (NN / 64)
#define YSWZ (KK * NN)   // u16 elements per batch in swizzled Y (65536)

typedef unsigned long long u64;
typedef unsigned int u32;
typedef unsigned short u16;
typedef __attribute__((ext_vector_type(8))) short s16x8;
typedef __attribute__((ext_vector_type(4))) float f32x4v;

__device__ __forceinline__ u32 bf16_rne(float f) {
    u32 u = __float_as_uint(f);
    return (u + 0x7FFFu + ((u >> 16) & 1u)) >> 16;
}
__device__ __forceinline__ float bf16_f32(u32 h) {
    return __uint_as_float(h << 16);
}
__device__ __forceinline__ long ypos(int f, int s) {
    return ((long)(s >> 8) << 12) + (s & 3) * 1024 + ((s >> 7) & 1) * 512 +
           f * 32 + ((s >> 5) & 3) * 8 + ((s >> 2) & 7);
}

// byte (8 mask bits) -> 8 bf16 {0,1} packed in s16x8 (elem i = bit i)
__device__ __forceinline__ s16x8 expand8(u32 byt) {
    u32 n0 = byt & 0xFu, n1 = (byt >> 4) & 0xFu;
    u32 t0 = (n0 * 0x204081u) & 0x01010101u;
    u32 t1 = (n1 * 0x204081u) & 0x01010101u;
    u32 m0 = (t0 << 7) - t0;
    u32 m1 = (t1 << 7) - t1;
    union { u32 w[4]; s16x8 v; } u;
    u.w[0] = __builtin_amdgcn_perm(0u, m0, 0x0C010C00u) << 7;
    u.w[1] = __builtin_amdgcn_perm(0u, m0, 0x0C030C02u) << 7;
    u.w[2] = __builtin_amdgcn_perm(0u, m1, 0x0C010C00u) << 7;
    u.w[3] = __builtin_amdgcn_perm(0u, m1, 0x0C030C02u) << 7;
    return u.v;
}

// ---------------------------------------------------------------- prep ------
__global__ __launch_bounds__(256)
void prep_kernel(const float* __restrict__ labels, u16* __restrict__ ysw0) {
    int gid = blockIdx.x * 256 + threadIdx.x;            // 65536 tasks
    int s4 = (gid & (NN / 4 - 1)) * 4;
    int f  = (gid >> 10) & (KK - 1);
    int b  = gid >> 14;
    long base = (long)b * YSWZ + ypos(f, s4);            // s4 mult of 4: +j*1024
    const float* lp = labels + ((long)b * NN + s4) * KK + f;
#pragma unroll
    for (int j = 0; j < 4; ++j)
        ysw0[base + j * 1024] = (u16)bf16_rne(lp[j * KK]);
}

// ----------------------------------------------------------- spmm (MFMA) ----
// grid = BB*(NN/16) = 1024 blocks of 256 threads (4 waves, 4 blocks/CU).
// PASS 1: fused own-row pack (LDS masks) + spmm; coalesced 8KB bits store.
// PASS 2: spmm from block-contiguous bits, writes ysw2.
// PASS 3: spmm + fused combine, vectorized epilogue.
template<int PASS>
__global__ __launch_bounds__(256, 4)
void spmm_k(const int* __restrict__ lig, u64* __restrict__ bits,
            const u16* __restrict__ yin, u16* __restrict__ yout,
            const u16* __restrict__ ysw1, const u16* __restrict__ ysw2,
            const float* __restrict__ labels, const float* __restrict__ ker,
            float* __restrict__ out)
{
    __shared__ float red[3][4][64];
    __shared__ u64 bl[64][16];                   // PASS1 masks [word][row] 8KB
    __shared__ float t1[16][16], t2[16][16], t3[16][16];  // PASS3 tiles 3KB
    const int bid = blockIdx.x;
    const int rt  = bid & (NN / 16 - 1);
    const int b   = bid >> 8;
    const int tid = threadIdx.x;
    const int lane = tid & 63, ss = tid >> 6;
    const int n16 = lane & 15, g = lane >> 4;
    const int row0 = rt * 16;

    // B fragments (independent of pack): issue first 4 segments NOW so they
    // ride under PASS1's HBM stream.
    const u16* yb = yin + (long)b * YSWZ + (ss * 16) * 1024 + n16 * 32 + g * 8;
    s16x8 p0[4], p1[4];
#pragma unroll
    for (int i = 0; i < 4; ++i) {
        p0[i] = *(const s16x8*)(yb + i * 1024);
        p1[i] = *(const s16x8*)(yb + i * 1024 + 512);
    }

    if (PASS == 1) {
        // pack own 16 rows: wave ss handles i=0..63 -> row=i&15, w4=ss*4+(i>>4)
        const int* lrow = lig + ((long)b * NN + row0) * NN;
        auto laddr = [&](int i) {
            int row = i & 15, w4 = ss * 4 + (i >> 4);
            return (const int4*)(lrow + (long)row * NN + w4 * 256 + lane * 4);
        };
        int4 v = *laddr(0);
        for (int i = 0; i < 64; ++i) {
            int4 vn;
            if (i + 1 < 64) vn = *laddr(i + 1);
            u64 m0 = __ballot(v.x >= 1);
            u64 m1 = __ballot(v.y >= 1);
            u64 m2 = __ballot(v.z >= 1);
            u64 m3 = __ballot(v.w >= 1);
            if (lane == 0) {
                int row = i & 15, wq = (ss * 4 + (i >> 4)) * 4;
                bl[wq + 0][row] = m0; bl[wq + 1][row] = m1;
                bl[wq + 2][row] = m2; bl[wq + 3][row] = m3;
            }
            v = vn;
        }
        __syncthreads();
        // coalesced 8KB burst: block-contiguous bits tile
        {
            uint4* dst = (uint4*)(bits + (long)(b * (NN / 16) + rt) * 1024);
            const uint4* src = (const uint4*)&bl[0][0];
            dst[tid]       = src[tid];
            dst[tid + 256] = src[tid + 256];
        }
    }

    // masks for this wave's 16 words
    u64 wcs[16];
    if (PASS == 1) {
#pragma unroll
        for (int wi = 0; wi < 16; ++wi) wcs[wi] = bl[ss * 16 + wi][n16];
    } else {
        const u64* bb = bits + ((long)(b * (NN / 16) + rt) * 64 + ss * 16) * 16 + n16;
#pragma unroll
        for (int wi = 0; wi < 16; ++wi) wcs[wi] = bb[wi * 16];
    }

    f32x4v accA = {0.f, 0.f, 0.f, 0.f}, accB = {0.f, 0.f, 0.f, 0.f};
#pragma unroll
    for (int wi = 0; wi < 16; ++wi) {
        const int slot = wi & 3;
        s16x8 b0 = p0[slot], b1 = p1[slot];
        if (wi + 4 < 16) {
            p0[slot] = *(const s16x8*)(yb + (wi + 4) * 1024);
            p1[slot] = *(const s16x8*)(yb + (wi + 4) * 1024 + 512);
        }
        u64 h = wcs[wi] >> (g * 8);
        u32 lo8 = (u32)h & 0xFFu;
        u32 hi8 = ((u32)(h >> 32)) & 0xFFu;
        accA = __builtin_amdgcn_mfma_f32_16x16x32_bf16(expand8(lo8), b0, accA, 0, 0, 0);
        accB = __builtin_amdgcn_mfma_f32_16x16x32_bf16(expand8(hi8), b1, accB, 0, 0, 0);
    }

    f32x4v acc;
#pragma unroll
    for (int r = 0; r < 4; ++r) acc[r] = accA[r] + accB[r];

    // PASS3: issue Y1/Y2 readbacks early (hide latency under reduce)
    const int s0 = row0 + 4 * g;
    const long ybase = (long)b * YSWZ + ypos(n16, s0);
    float y1v[4], y2v[4];
    if (PASS == 3 && ss == 0) {
#pragma unroll
        for (int r = 0; r < 4; ++r) {
            y1v[r] = bf16_f32(ysw1[ybase + r * 1024]);
            y2v[r] = bf16_f32(ysw2[ybase + r * 1024]);
        }
    }

    if (ss != 0) {
#pragma unroll
        for (int r = 0; r < 4; ++r) red[ss - 1][r][lane] = acc[r];
    }
    __syncthreads();
    if (ss == 0) {
#pragma unroll
        for (int r = 0; r < 4; ++r)
            acc[r] += red[0][r][lane] + red[1][r][lane] + red[2][r][lane];

        if (PASS < 3) {
#pragma unroll
            for (int r = 0; r < 4; ++r)
                yout[ybase + r * 1024] = (u16)bf16_rne(acc[r]);
        } else {
            // park tiles: row-in-tile = 4g+r, col = n16 (m89-verified D layout)
#pragma unroll
            for (int r = 0; r < 4; ++r) {
                t1[4 * g + r][n16] = y1v[r];
                t2[4 * g + r][n16] = y2v[r];
                t3[4 * g + r][n16] = acc[r];
            }
        }
    }

    if (PASS == 3) {
        __syncthreads();
        // all 256 threads: 2 coalesced float4 chunks each.
#pragma unroll
        for (int j = 0; j < 2; ++j) {
            int fi = tid + j * 256;
            int c = fi >> 6, row = (fi >> 2) & 15, k4 = fi & 3;
            const float4* kf = (const float4*)ker;
            float4 a = kf[(c * TT + 0) * 4 + k4];
            float4 d = kf[(c * TT + 1) * 4 + k4];
            float4 e = kf[(c * TT + 2) * 4 + k4];
            float4 e1, e2, e3;
            e1.x = a.x + d.x + e.x;               e1.y = a.y + d.y + e.y;
            e1.z = a.z + d.z + e.z;               e1.w = a.w + d.w + e.w;
            e2.x = a.x*d.x + a.x*e.x + d.x*e.x;   e2.y = a.y*d.y + a.y*e.y + d.y*e.y;
            e2.z = a.z*d.z + a.z*e.z + d.z*e.z;   e2.w = a.w*d.w + a.w*e.w + d.w*e.w;
            e3.x = a.x * d.x * e.x;               e3.y = a.y * d.y * e.y;
            e3.z = a.z * d.z * e.z;               e3.w = a.w * d.w * e.w;
            float4 y0 = *(const float4*)(labels + ((long)b * NN + row0 + row) * KK + k4 * 4);
            float4 v1 = *(const float4*)&t1[row][k4 * 4];
            float4 v2 = *(const float4*)&t2[row][k4 * 4];
            float4 v3 = *(const float4*)&t3[row][k4 * 4];
            float4 r;
            r.x = y0.x + e1.x * v1.x + e2.x * v2.x + e3.x * v3.x;
            r.y = y0.y + e1.y * v1.y + e2.y * v2.y + e3.y * v3.y;
            r.z = y0.z + e1.z * v1.z + e2.z * v2.z + e3.z * v3.z;
            r.w = y0.w + e1.w * v1.w + e2.w * v2.w + e3.w * v3.w;
            *(float4*)(out + (((long)b * CC + c) * NN + row0 + row) * KK + k4 * 4) = r;
        }
    }
}

// --------------------------------------------------------------- launch -----
extern "C" void kernel_launch(void* const* d_in, const int* in_sizes, int n_in,
                              void* d_out, int out_size, void* d_ws, size_t ws_size,
                              hipStream_t stream) {
    const float* labels = (const float*)d_in[0];   // [B,N,K] f32
    const int*   lig    = (const int*)d_in[1];     // [B,N,N] i32
    const float* ker    = (const float*)d_in[2];   // [C,T,K] f32
    float* out = (float*)d_out;

    u64* bits = (u64*)d_ws;                        // 8 MB
    u16* ysw0 = (u16*)((char*)d_ws + (long)BB * WPR * NN * 8);
    u16* ysw1 = ysw0 + (long)BB * YSWZ;
    u16* ysw2 = ysw1 + (long)BB * YSWZ;

    hipLaunchKernelGGL(prep_kernel, dim3(256), dim3(256), 0, stream,
                       labels, ysw0);

    dim3 sgrid(BB * (NN / 16));                    // 1024 blocks
    hipLaunchKernelGGL((spmm_k<1>), sgrid, dim3(256), 0, stream,
                       lig, bits, ysw0, ysw1, (const u16*)nullptr,
                       (const u16*)nullptr, (const float*)nullptr,
                       (const float*)nullptr, (float*)nullptr);
    hipLaunchKernelGGL((spmm_k<2>), sgrid, dim3(256), 0, stream,
                       (const int*)nullptr, bits, ysw1, ysw2,
                       (const u16*)nullptr, (const u16*)nullptr,
                       (const float*)nullptr, (const float*)nullptr,
                       (float*)nullptr);
    hipLaunchKernelGGL((spmm_k<3>), sgrid, dim3(256), 0, stream,
                       (const int*)nullptr, bits, ysw2, (u16*)nullptr,
                       ysw1, ysw2, labels, ker, out);
}

// Round 16
// 77.262 us; speedup vs baseline: 8.6339x; 1.0665x over previous
//
#include <hip/hip_runtime.h>

// WL-conv factorized:  out[b,c,n,k] = Y0 + e1[c,k]*Y1 + e2[c,k]*Y2 + e3[c,k]*Y3
// with Ym = M^m labels and e_m the elementary symmetric polynomials of
// kernels[c,0..2,k] (per-step operators I + k_t∘M commute).
//
// 4 stream-ordered kernels:
//   prep: labels -> swizzled bf16 Y0                       [R15, unchanged]
//   K1  : fused own-row pack + Y1 = M Y0, coalesced 8KB bits tile
//                                                          [R15, unchanged]
//   K2/K3: NEW 32-ROW BLOCKS (512 blocks, 2/CU, bounds(256,2)): two 16-row
//         tiles share each B-fragment load -> per-pass L2 B-traffic halves
//         (128->64 MB). Masks + B in depth-4 rolling register pipelines.
//         K3 fuses combine with vectorized float4 epilogue.
// bits layout: bits[((b*256+rt)*64 + w)*16 + r]  (block-coalesced tiles)
// Y chained in ypos-permuted MFMA-B-fragment layout (coalesced 1KB B loads).
//
// d_out (8 MB): final output only.
// d_ws: bits 8MB | ysw0 | ysw1 | ysw2 (0.5 MB each, swizzled bf16).

#define BB 4
#define NN 4096
#define KK 16
#define CC 8
#define TT 3
#define WPR (NN / 64)
#define YSWZ (KK * NN)   // u16 elements per batch in swizzled Y (65536)

typedef unsigned long long u64;
typedef unsigned int u32;
typedef unsigned short u16;
typedef __attribute__((ext_vector_type(8))) short s16x8;
typedef __attribute__((ext_vector_type(4))) float f32x4v;

__device__ __forceinline__ u32 bf16_rne(float f) {
    u32 u = __float_as_uint(f);
    return (u + 0x7FFFu + ((u >> 16) & 1u)) >> 16;
}
__device__ __forceinline__ float bf16_f32(u32 h) {
    return __uint_as_float(h << 16);
}
__device__ __forceinline__ long ypos(int f, int s) {
    return ((long)(s >> 8) << 12) + (s & 3) * 1024 + ((s >> 7) & 1) * 512 +
           f * 32 + ((s >> 5) & 3) * 8 + ((s >> 2) & 7);
}

// byte (8 mask bits) -> 8 bf16 {0,1} packed in s16x8 (elem i = bit i)
__device__ __forceinline__ s16x8 expand8(u32 byt) {
    u32 n0 = byt & 0xFu, n1 = (byt >> 4) & 0xFu;
    u32 t0 = (n0 * 0x204081u) & 0x01010101u;
    u32 t1 = (n1 * 0x204081u) & 0x01010101u;
    u32 m0 = (t0 << 7) - t0;
    u32 m1 = (t1 << 7) - t1;
    union { u32 w[4]; s16x8 v; } u;
    u.w[0] = __builtin_amdgcn_perm(0u, m0, 0x0C010C00u) << 7;
    u.w[1] = __builtin_amdgcn_perm(0u, m0, 0x0C030C02u) << 7;
    u.w[2] = __builtin_amdgcn_perm(0u, m1, 0x0C010C00u) << 7;
    u.w[3] = __builtin_amdgcn_perm(0u, m1, 0x0C030C02u) << 7;
    return u.v;
}

// ---------------------------------------------------------------- prep ------
__global__ __launch_bounds__(256)
void prep_kernel(const float* __restrict__ labels, u16* __restrict__ ysw0) {
    int gid = blockIdx.x * 256 + threadIdx.x;            // 65536 tasks
    int s4 = (gid & (NN / 4 - 1)) * 4;
    int f  = (gid >> 10) & (KK - 1);
    int b  = gid >> 14;
    long base = (long)b * YSWZ + ypos(f, s4);            // s4 mult of 4: +j*1024
    const float* lp = labels + ((long)b * NN + s4) * KK + f;
#pragma unroll
    for (int j = 0; j < 4; ++j)
        ysw0[base + j * 1024] = (u16)bf16_rne(lp[j * KK]);
}

// ------------------------------------------------------- K1 (pack + spmm) ---
__global__ __launch_bounds__(256, 4)
void spmm1_k(const int* __restrict__ lig, u64* __restrict__ bits,
             const u16* __restrict__ yin, u16* __restrict__ yout)
{
    __shared__ float red[3][4][64];
    __shared__ u64 bl[64][16];                   // masks [word][row] 8KB
    const int bid = blockIdx.x;
    const int rt  = bid & (NN / 16 - 1);
    const int b   = bid >> 8;
    const int tid = threadIdx.x;
    const int lane = tid & 63, ss = tid >> 6;
    const int n16 = lane & 15, g = lane >> 4;
    const int row0 = rt * 16;

    const u16* yb = yin + (long)b * YSWZ + (ss * 16) * 1024 + n16 * 32 + g * 8;
    s16x8 p0[4], p1[4];
#pragma unroll
    for (int i = 0; i < 4; ++i) {
        p0[i] = *(const s16x8*)(yb + i * 1024);
        p1[i] = *(const s16x8*)(yb + i * 1024 + 512);
    }

    {
        const int* lrow = lig + ((long)b * NN + row0) * NN;
        auto laddr = [&](int i) {
            int row = i & 15, w4 = ss * 4 + (i >> 4);
            return (const int4*)(lrow + (long)row * NN + w4 * 256 + lane * 4);
        };
        int4 v = *laddr(0);
        for (int i = 0; i < 64; ++i) {
            int4 vn;
            if (i + 1 < 64) vn = *laddr(i + 1);
            u64 m0 = __ballot(v.x >= 1);
            u64 m1 = __ballot(v.y >= 1);
            u64 m2 = __ballot(v.z >= 1);
            u64 m3 = __ballot(v.w >= 1);
            if (lane == 0) {
                int row = i & 15, wq = (ss * 4 + (i >> 4)) * 4;
                bl[wq + 0][row] = m0; bl[wq + 1][row] = m1;
                bl[wq + 2][row] = m2; bl[wq + 3][row] = m3;
            }
            v = vn;
        }
        __syncthreads();
        uint4* dst = (uint4*)(bits + (long)(b * (NN / 16) + rt) * 1024);
        const uint4* src = (const uint4*)&bl[0][0];
        dst[tid]       = src[tid];
        dst[tid + 256] = src[tid + 256];
    }

    u64 wcs[16];
#pragma unroll
    for (int wi = 0; wi < 16; ++wi) wcs[wi] = bl[ss * 16 + wi][n16];

    f32x4v accA = {0.f, 0.f, 0.f, 0.f}, accB = {0.f, 0.f, 0.f, 0.f};
#pragma unroll
    for (int wi = 0; wi < 16; ++wi) {
        const int slot = wi & 3;
        s16x8 b0 = p0[slot], b1 = p1[slot];
        if (wi + 4 < 16) {
            p0[slot] = *(const s16x8*)(yb + (wi + 4) * 1024);
            p1[slot] = *(const s16x8*)(yb + (wi + 4) * 1024 + 512);
        }
        u64 h = wcs[wi] >> (g * 8);
        accA = __builtin_amdgcn_mfma_f32_16x16x32_bf16(expand8((u32)h & 0xFFu), b0, accA, 0, 0, 0);
        accB = __builtin_amdgcn_mfma_f32_16x16x32_bf16(expand8(((u32)(h >> 32)) & 0xFFu), b1, accB, 0, 0, 0);
    }

    f32x4v acc;
#pragma unroll
    for (int r = 0; r < 4; ++r) acc[r] = accA[r] + accB[r];

    if (ss != 0) {
#pragma unroll
        for (int r = 0; r < 4; ++r) red[ss - 1][r][lane] = acc[r];
    }
    __syncthreads();
    if (ss == 0) {
#pragma unroll
        for (int r = 0; r < 4; ++r)
            acc[r] += red[0][r][lane] + red[1][r][lane] + red[2][r][lane];
        const int s0 = row0 + 4 * g;
        const long ybase = (long)b * YSWZ + ypos(n16, s0);
#pragma unroll
        for (int r = 0; r < 4; ++r)
            yout[ybase + r * 1024] = (u16)bf16_rne(acc[r]);
    }
}

// --------------------------------------------- K2/K3: 32-row blocks ---------
// grid = BB*(NN/32) = 512 blocks of 256 threads, 2 blocks/CU (bounds 256,2).
// Two 16-row tiles (rt0=2*rtp, rt1=2*rtp+1) share every B-fragment load.
// Masks + B fragments in depth-4 rolling register pipelines.
template<bool LAST>
__global__ __launch_bounds__(256, 2)
void spmm2_k(const u64* __restrict__ bits, const u16* __restrict__ yin,
             u16* __restrict__ yout, const u16* __restrict__ ysw1,
             const u16* __restrict__ ysw2, const float* __restrict__ labels,
             const float* __restrict__ ker, float* __restrict__ out)
{
    __shared__ float red[2][3][4][64];                    // 6 KB
    __shared__ float t1[32][16], t2[32][16], t3[32][16];  // 6 KB (LAST)
    const int bid = blockIdx.x;
    const int rtp = bid & (NN / 32 - 1);
    const int b   = bid >> 7;
    const int tid = threadIdx.x;
    const int lane = tid & 63, ss = tid >> 6;
    const int n16 = lane & 15, g = lane >> 4;
    const int row0 = rtp * 32;
    const int rt0 = 2 * rtp, rt1 = 2 * rtp + 1;

    const u64* bb0 = bits + ((long)(b * (NN / 16) + rt0) * 64 + ss * 16) * 16 + n16;
    const u64* bb1 = bits + ((long)(b * (NN / 16) + rt1) * 64 + ss * 16) * 16 + n16;
    const u16* yb  = yin + (long)b * YSWZ + (ss * 16) * 1024 + n16 * 32 + g * 8;

    s16x8 p0[4], p1[4]; u64 m0[4], m1[4];
#pragma unroll
    for (int i = 0; i < 4; ++i) {
        p0[i] = *(const s16x8*)(yb + i * 1024);
        p1[i] = *(const s16x8*)(yb + i * 1024 + 512);
        m0[i] = bb0[i * 16];
        m1[i] = bb1[i * 16];
    }

    f32x4v accA0 = {0.f,0.f,0.f,0.f}, accB0 = {0.f,0.f,0.f,0.f};
    f32x4v accA1 = {0.f,0.f,0.f,0.f}, accB1 = {0.f,0.f,0.f,0.f};
#pragma unroll
    for (int wi = 0; wi < 16; ++wi) {
        const int slot = wi & 3;
        s16x8 b0 = p0[slot], b1 = p1[slot];
        u64 h0 = m0[slot], h1 = m1[slot];
        if (wi + 4 < 16) {
            p0[slot] = *(const s16x8*)(yb + (wi + 4) * 1024);
            p1[slot] = *(const s16x8*)(yb + (wi + 4) * 1024 + 512);
            m0[slot] = bb0[(wi + 4) * 16];
            m1[slot] = bb1[(wi + 4) * 16];
        }
        u64 ha = h0 >> (g * 8), hb = h1 >> (g * 8);
        accA0 = __builtin_amdgcn_mfma_f32_16x16x32_bf16(expand8((u32)ha & 0xFFu), b0, accA0, 0, 0, 0);
        accB0 = __builtin_amdgcn_mfma_f32_16x16x32_bf16(expand8(((u32)(ha >> 32)) & 0xFFu), b1, accB0, 0, 0, 0);
        accA1 = __builtin_amdgcn_mfma_f32_16x16x32_bf16(expand8((u32)hb & 0xFFu), b0, accA1, 0, 0, 0);
        accB1 = __builtin_amdgcn_mfma_f32_16x16x32_bf16(expand8(((u32)(hb >> 32)) & 0xFFu), b1, accB1, 0, 0, 0);
    }

    f32x4v acc0, acc1;
#pragma unroll
    for (int r = 0; r < 4; ++r) { acc0[r] = accA0[r] + accB0[r];
                                  acc1[r] = accA1[r] + accB1[r]; }

    // LAST: issue Y1/Y2 readbacks early (hide latency under reduce)
    const int s0a = row0 + 4 * g;            // tile0 rows
    const int s0b = row0 + 16 + 4 * g;       // tile1 rows
    const long yba = (long)b * YSWZ + ypos(n16, s0a);
    const long ybb = (long)b * YSWZ + ypos(n16, s0b);
    float y1a[4], y2a[4], y1b[4], y2b[4];
    if (LAST && ss == 0) {
#pragma unroll
        for (int r = 0; r < 4; ++r) {
            y1a[r] = bf16_f32(ysw1[yba + r * 1024]);
            y2a[r] = bf16_f32(ysw2[yba + r * 1024]);
            y1b[r] = bf16_f32(ysw1[ybb + r * 1024]);
            y2b[r] = bf16_f32(ysw2[ybb + r * 1024]);
        }
    }

    if (ss != 0) {
#pragma unroll
        for (int r = 0; r < 4; ++r) {
            red[0][ss - 1][r][lane] = acc0[r];
            red[1][ss - 1][r][lane] = acc1[r];
        }
    }
    __syncthreads();
    if (ss == 0) {
#pragma unroll
        for (int r = 0; r < 4; ++r) {
            acc0[r] += red[0][0][r][lane] + red[0][1][r][lane] + red[0][2][r][lane];
            acc1[r] += red[1][0][r][lane] + red[1][1][r][lane] + red[1][2][r][lane];
        }
        if (!LAST) {
#pragma unroll
            for (int r = 0; r < 4; ++r) {
                yout[yba + r * 1024] = (u16)bf16_rne(acc0[r]);
                yout[ybb + r * 1024] = (u16)bf16_rne(acc1[r]);
            }
        } else {
            // park tiles: row-in-tile = 4g+r (+16 for tile1), col = n16
#pragma unroll
            for (int r = 0; r < 4; ++r) {
                t1[4 * g + r][n16]      = y1a[r];
                t2[4 * g + r][n16]      = y2a[r];
                t3[4 * g + r][n16]      = acc0[r];
                t1[16 + 4 * g + r][n16] = y1b[r];
                t2[16 + 4 * g + r][n16] = y2b[r];
                t3[16 + 4 * g + r][n16] = acc1[r];
            }
        }
    }

    if (LAST) {
        __syncthreads();
        // 1024 float4 chunks: fi = tid + j*256; c = fi>>7, row = (fi>>2)&31,
        // k4 = fi&3. Coalesced per-channel stores.
#pragma unroll
        for (int j = 0; j < 4; ++j) {
            int fi = tid + j * 256;
            int c = fi >> 7, row = (fi >> 2) & 31, k4 = fi & 3;
            const float4* kf = (const float4*)ker;
            float4 a = kf[(c * TT + 0) * 4 + k4];
            float4 d = kf[(c * TT + 1) * 4 + k4];
            float4 e = kf[(c * TT + 2) * 4 + k4];
            float4 e1, e2, e3;
            e1.x = a.x + d.x + e.x;               e1.y = a.y + d.y + e.y;
            e1.z = a.z + d.z + e.z;               e1.w = a.w + d.w + e.w;
            e2.x = a.x*d.x + a.x*e.x + d.x*e.x;   e2.y = a.y*d.y + a.y*e.y + d.y*e.y;
            e2.z = a.z*d.z + a.z*e.z + d.z*e.z;   e2.w = a.w*d.w + a.w*e.w + d.w*e.w;
            e3.x = a.x * d.x * e.x;               e3.y = a.y * d.y * e.y;
            e3.z = a.z * d.z * e.z;               e3.w = a.w * d.w * e.w;
            float4 y0 = *(const float4*)(labels + ((long)b * NN + row0 + row) * KK + k4 * 4);
            float4 v1 = *(const float4*)&t1[row][k4 * 4];
            float4 v2 = *(const float4*)&t2[row][k4 * 4];
            float4 v3 = *(const float4*)&t3[row][k4 * 4];
            float4 r;
            r.x = y0.x + e1.x * v1.x + e2.x * v2.x + e3.x * v3.x;
            r.y = y0.y + e1.y * v1.y + e2.y * v2.y + e3.y * v3.y;
            r.z = y0.z + e1.z * v1.z + e2.z * v2.z + e3.z * v3.z;
            r.w = y0.w + e1.w * v1.w + e2.w * v2.w + e3.w * v3.w;
            *(float4*)(out + (((long)b * CC + c) * NN + row0 + row) * KK + k4 * 4) = r;
        }
    }
}

// --------------------------------------------------------------- launch -----
extern "C" void kernel_launch(void* const* d_in, const int* in_sizes, int n_in,
                              void* d_out, int out_size, void* d_ws, size_t ws_size,
                              hipStream_t stream) {
    const float* labels = (const float*)d_in[0];   // [B,N,K] f32
    const int*   lig    = (const int*)d_in[1];     // [B,N,N] i32
    const float* ker    = (const float*)d_in[2];   // [C,T,K] f32
    float* out = (float*)d_out;

    u64* bits = (u64*)d_ws;                        // 8 MB
    u16* ysw0 = (u16*)((char*)d_ws + (long)BB * WPR * NN * 8);
    u16* ysw1 = ysw0 + (long)BB * YSWZ;
    u16* ysw2 = ysw1 + (long)BB * YSWZ;

    hipLaunchKernelGGL(prep_kernel, dim3(256), dim3(256), 0, stream,
                       labels, ysw0);

    hipLaunchKernelGGL(spmm1_k, dim3(BB * (NN / 16)), dim3(256), 0, stream,
                       lig, bits, ysw0, ysw1);
    hipLaunchKernelGGL((spmm2_k<false>), dim3(BB * (NN / 32)), dim3(256), 0,
                       stream, bits, ysw1, ysw2, (const u16*)nullptr,
                       (const u16*)nullptr, (const float*)nullptr,
                       (const float*)nullptr, (float*)nullptr);
    hipLaunchKernelGGL((spmm2_k<true>),  dim3(BB * (NN / 32)), dim3(256), 0,
                       stream, bits, ysw2, (u16*)nullptr, ysw1, ysw2,
                       labels, ker, out);
}